// Round 7
// baseline (459.675 us; speedup 1.0000x reference)
//
#include <hip/hip_runtime.h>

typedef unsigned short u16;
typedef unsigned int u32;
typedef __attribute__((ext_vector_type(8))) short bf16x8;
typedef __attribute__((ext_vector_type(4))) float f32x4;

__device__ __forceinline__ u16 f2bf(float f) {
  u32 u = __float_as_uint(f);
  u32 r = (u + 0x7FFFu + ((u >> 16) & 1u)) >> 16;  // RTNE
  return (u16)r;
}

__device__ __forceinline__ void gl_lds16(const u16* g, u16* l) {
  __builtin_amdgcn_global_load_lds(
      (const __attribute__((address_space(1))) u32*)g,
      (__attribute__((address_space(3))) u32*)l, 16, 0, 0);
}

// ---------------- prep: U fp32 -> bf16 ----------------
__global__ __launch_bounds__(256) void cvt_bf16(const float* __restrict__ src,
                                                u16* __restrict__ dst, int n4) {
  int g = blockIdx.x * 256 + threadIdx.x;
  if (g < n4) {
    float4 v = ((const float4*)src)[g];
    ushort4 o;
    o.x = f2bf(v.x); o.y = f2bf(v.y); o.z = f2bf(v.z); o.w = f2bf(v.w);
    ((ushort4*)dst)[g] = o;
  }
}

// ---------------- prep: x fp32 -> Xb bf16 [b][l][d] and XT bf16 [b][d][l] ----------------
__global__ __launch_bounds__(256) void prep_x(const float* __restrict__ x,
                                              u16* __restrict__ Xb,
                                              u16* __restrict__ XT) {
  __shared__ u16 t[32][33];
  const int b = blockIdx.z;
  const int l0 = blockIdx.y * 32;
  const int d0 = blockIdx.x * 32;
  const int j = threadIdx.x & 31;
  const int t5 = threadIdx.x >> 5;
#pragma unroll
  for (int r = 0; r < 4; r++) {
    int i = r * 8 + t5;
    float v = x[((size_t)b * 2048 + l0 + i) * 512 + d0 + j];
    u16 h = f2bf(v);
    t[i][j] = h;
    Xb[((size_t)b * 2048 + l0 + i) * 512 + d0 + j] = h;
  }
  __syncthreads();
#pragma unroll
  for (int r = 0; r < 4; r++) {
    int i = r * 8 + t5;
    XT[((size_t)b * 512 + d0 + i) * 2048 + l0 + j] = t[j][i];
  }
}

__global__ __launch_bounds__(256) void zero_f32(float* __restrict__ p, int n) {
  int g = blockIdx.x * 256 + threadIdx.x;
  if (g < n) p[g] = 0.f;
}

// ---------------- 128x128-tile batched GEMM: C[b] = A[b] @ B[b]^T ----------------
// m97-regime: BK=64, 4 waves (2x2, 64x64/wave), single-buffered 32 KiB LDS,
// swizzled rows (byte ^= (row&7)<<4), simple 2-barrier loop, 4 blocks/CU
// (128 KiB LDS, ~124 regs <= 512/4). Cross-block TLP hides staging drains,
// prologue cold-stages, and epilogues.
// EPI=0: out = bf16(exp(acc)) -> u16* stride N; fused rowsum atomicAdd into z
// EPI=2: out = acc / z[row]   -> float* stride N
template <int EPI>
__global__ __launch_bounds__(256, 4)
void gemm128(const u16* __restrict__ A, const u16* __restrict__ B,
             void* __restrict__ Cout, float* __restrict__ z,
             int Kstride, int nt, int N,
             size_t Ab_str, size_t Bb_str, size_t Cb_str, int gx, int gy) {
  __shared__ u16 lA[8192];   // [128 rows][64 k] swizzled, 16 KiB
  __shared__ u16 lB[8192];
  __shared__ float rz_lds[128];

  // flatten + XCD-bijective swizzle (nwg % 8 == 0 in all launches)
  const int nwg = gx * gy * gridDim.z;
  const int orig = blockIdx.x + gx * (blockIdx.y + gy * blockIdx.z);
  const int cpx = nwg >> 3;
  const int nid = (orig & 7) * cpx + (orig >> 3);
  const int bxi = nid % gx;
  const int byi = (nid / gx) % gy;
  const int bzi = nid / (gx * gy);
  const int m0 = byi * 128, n0 = bxi * 128;

  const u16* Ab = A + (size_t)bzi * Ab_str;
  const u16* Bb = B + (size_t)bzi * Bb_str;
  float* zb = z + (size_t)bzi * 8192;

  const int tid = threadIdx.x;
  const int l = tid & 63;
  const int w = tid >> 6;              // wave 0..3
  const int wy = w >> 1, wx = w & 1;   // 2x2 wave grid, 64x64 per wave

  // ---- staging constants (write side; inverse-swizzled global source) ----
  const int rowS = tid >> 3;                                  // 0..31
  const int cS = ((tid & 7) << 4) ^ ((rowS & 7) << 4);        // src byte col
  const u16* srcA0 = Ab + (size_t)(m0 + rowS) * Kstride + (cS >> 1);
  const u16* srcB0 = Bb + (size_t)(n0 + rowS) * Kstride + (cS >> 1);
  const size_t rsk = (size_t)32 * Kstride;   // 32-row skip (elems)

  // ---- read-side constants (swizzled ds_read addresses) ----
  const int fr = l & 15;                       // fragment row (within 16)
  const int X = (fr & 7) << 4;                 // swizzle mask (bytes)
  const int kb = (l >> 4) << 4;                // 0,16,32,48 byte col
  const int swz0 = (kb ^ X) >> 1;              // u16 units, k-slice 0
  const int swz1 = ((64 + kb) ^ X) >> 1;       // k-slice 1
  const int aRow = (wy * 64 + fr) * 64;        // u16 index of row base (m=0)
  const int bRow = (wx * 64 + fr) * 64;

  if (EPI == 2 && tid < 128) rz_lds[tid] = 1.f / zb[m0 + tid];

  f32x4 acc[4][4] = {};

  for (int t = 0; t < nt; ++t) {
#pragma unroll
    for (int j = 0; j < 4; j++) {
      gl_lds16(srcA0 + j * rsk + t * 64, &lA[tid * 8 + j * 2048]);
      gl_lds16(srcB0 + j * rsk + t * 64, &lB[tid * 8 + j * 2048]);
    }
    __syncthreads();   // drains vmcnt -> tile resident
#pragma unroll
    for (int ks = 0; ks < 2; ks++) {
      const int swz = ks ? swz1 : swz0;
      bf16x8 bfr[4], afr[4];
#pragma unroll
      for (int n = 0; n < 4; n++) bfr[n] = *(const bf16x8*)&lB[bRow + n * 1024 + swz];
#pragma unroll
      for (int m = 0; m < 4; m++) afr[m] = *(const bf16x8*)&lA[aRow + m * 1024 + swz];
#pragma unroll
      for (int m = 0; m < 4; m++)
#pragma unroll
        for (int n = 0; n < 4; n++)
          acc[m][n] = __builtin_amdgcn_mfma_f32_16x16x32_bf16(
              afr[m], bfr[n], acc[m][n], 0, 0, 0);
    }
    __syncthreads();   // reads done before next stage overwrites
  }

  // ---- epilogue ----
  const int rq = (l >> 4) * 4;  // C/D: col=lane&15, row=(lane>>4)*4+reg
#pragma unroll
  for (int m = 0; m < 4; m++) {
    const int lrow = wy * 64 + m * 16 + rq;    // local row in 128-tile
    const int grow = m0 + lrow;
    float rs[4] = {0.f, 0.f, 0.f, 0.f};
#pragma unroll
    for (int n = 0; n < 4; n++) {
      const int col = n0 + wx * 64 + n * 16 + fr;
#pragma unroll
      for (int r = 0; r < 4; r++) {
        const float v = acc[m][n][r];
        if (EPI == 0) {
          const float e = __expf(v);
          ((u16*)Cout)[(size_t)bzi * Cb_str + (size_t)(grow + r) * N + col] = f2bf(e);
          rs[r] += e;
        } else {
          ((float*)Cout)[(size_t)bzi * Cb_str + (size_t)(grow + r) * N + col] =
              v * rz_lds[lrow + r];
        }
      }
    }
    if (EPI == 0) {
#pragma unroll
      for (int s = 1; s < 16; s <<= 1)
#pragma unroll
        for (int r = 0; r < 4; r++) rs[r] += __shfl_xor(rs[r], s);
      if (fr == 0) {
#pragma unroll
        for (int r = 0; r < 4; r++) atomicAdd(&zb[grow + r], rs[r]);
      }
    }
  }
}

// B=8, L=2048, D=512, Y=8192
extern "C" void kernel_launch(void* const* d_in, const int* in_sizes, int n_in,
                              void* d_out, int out_size, void* d_ws, size_t ws_size,
                              hipStream_t stream) {
  const float* x = (const float*)d_in[0];   // [8][2048][512]
  const float* U = (const float*)d_in[1];   // [8192][512]
  if (n_in >= 2 && in_sizes[0] == 8192 * 512) {
    x = (const float*)d_in[1];
    U = (const float*)d_in[0];
  }
  float* out = (float*)d_out;               // [8][8192][512]
  char* ws = (char*)d_ws;

  // ws layout (bytes)
  u16* Ub = (u16*)ws;                       // 8 MiB
  u16* Xb = (u16*)(ws + 8388608);           // 16 MiB
  u16* XT = (u16*)(ws + 25165824);          // 16 MiB
  u16* P  = (u16*)(ws + 41943040);          // all-batch: 256 MiB
  const size_t need_all = 41943040ull + 268435456ull + 262144ull;

  cvt_bf16<<<4096, 256, 0, stream>>>(U, Ub, (8192 * 512) / 4);
  prep_x<<<dim3(16, 64, 8), 256, 0, stream>>>(x, Xb, XT);

  if (ws_size >= need_all) {
    float* z = (float*)(ws + 41943040 + 268435456);
    zero_f32<<<256, 256, 0, stream>>>(z, 8 * 8192);
    // P[b] = exp(U @ x_b^T), fused rowsum -> z[b]: M=8192, N=2048, K=512
    gemm128<0><<<dim3(16, 64, 8), 256, 0, stream>>>(
        Ub, Xb, P, z, 512, 8, 2048,
        0, (size_t)2048 * 512, (size_t)8192 * 2048, 16, 64);
    // out[b] = (P[b] @ XT_b^T) / z[b]: M=8192, N=512, K=2048
    gemm128<2><<<dim3(4, 64, 8), 256, 0, stream>>>(
        P, XT, out, z, 2048, 32, 512,
        (size_t)8192 * 2048, (size_t)512 * 2048, (size_t)8192 * 512, 4, 64);
  } else {
    // fallback: per-batch P (32 MiB)
    float* z = (float*)(ws + 41943040 + 33554432);
    zero_f32<<<256, 256, 0, stream>>>(z, 8 * 8192);
    for (int b = 0; b < 8; b++) {
      gemm128<0><<<dim3(16, 64, 1), 256, 0, stream>>>(
          Ub, Xb + (size_t)b * 2048 * 512, P, z + b * 8192, 512, 8, 2048,
          0, 0, 0, 16, 64);
      gemm128<2><<<dim3(4, 64, 1), 256, 0, stream>>>(
          P, XT + (size_t)b * 512 * 2048, out + (size_t)b * 8192 * 512,
          z + b * 8192, 2048, 32, 512, 0, 0, 0, 4, 64);
    }
  }
}